// Round 1
// baseline (840.449 us; speedup 1.0000x reference)
//
#include <hip/hip_runtime.h>
#include <hip/hip_bf16.h>
#include <math.h>

#define N_NODES 32768
#define N_EDGES 524288
#define HID 128

// ---------- helpers ----------
__device__ __forceinline__ unsigned ordkey(float f) {
  unsigned u = __float_as_uint(f);
  return (u & 0x80000000u) ? ~u : (u | 0x80000000u);
}
__device__ __forceinline__ float unordkey(unsigned k) {
  unsigned u = (k & 0x80000000u) ? (k & 0x7FFFFFFFu) : ~k;
  return __uint_as_float(u);
}

// ---------- prep: Wcat[128x512] = [Wl | Wr | We_top | We_bot], bcat, bpost2 ----------
__global__ void prep_kernel(const float* __restrict__ Wl, const float* __restrict__ bl,
                            const float* __restrict__ Wr, const float* __restrict__ br,
                            const float* __restrict__ We, const float* __restrict__ gat_bias,
                            const float* __restrict__ Wpost, const float* __restrict__ bpost,
                            float* __restrict__ Wcat, float* __restrict__ bcat,
                            float* __restrict__ bpost2) {
  int b = blockIdx.x, t = threadIdx.x;
  if (b < 256) {
    int id = b * 256 + t;           // 0..65535
    int k = id >> 9, j = id & 511;
    float v;
    if (j < 128)      v = Wl[k * 128 + j];
    else if (j < 256) v = Wr[k * 128 + (j - 128)];
    else if (j < 384) v = We[k * 128 + (j - 256)];
    else              v = We[(128 + k) * 128 + (j - 384)];
    Wcat[id] = v;
  } else if (b == 256) {
    for (int j = t; j < 512; j += 256)
      bcat[j] = (j < 128) ? bl[j] : (j < 256) ? br[j - 128] : 0.0f;
  } else {
    if (t < 128) {
      float s = bpost[t];
      for (int k = 0; k < 128; ++k) s += gat_bias[k] * Wpost[k * 128 + t];
      bpost2[t] = s;
    }
  }
}

// ---------- generic fp32 GEMM: C[M x Nc] = A[M x 128] @ W[128 x Nc] (+bias)(gelu?)(+resid) ----------
// grid (Nc/64, M/64), block 256. 64x64 tile, 4x4 per thread, full K=128 in LDS.
__global__ __launch_bounds__(256) void gemm128(const float* __restrict__ A,
                                               const float* __restrict__ W,
                                               const float* __restrict__ bias,
                                               const float* __restrict__ resid,
                                               float* __restrict__ C, int Ncols, int act) {
  __shared__ float As[128 * 64];   // [k][m], XOR-swizzled on m
  __shared__ float Ws[128 * 64];   // [k][n]
  const int tid = threadIdx.x;
  const int bm = blockIdx.y * 64;
  const int bn = blockIdx.x * 64;

  // stage A tile (coalesced float4 along k), transpose into As[k][m^sw]
  {
    int kv = tid & 31;            // float4 index along k
    int rb = tid >> 5;            // 0..7
    int sw = (kv & 7) << 2;
#pragma unroll
    for (int it = 0; it < 8; ++it) {
      int r = it * 8 + rb;
      float4 v = *(const float4*)&A[(size_t)(bm + r) * 128 + kv * 4];
      int k0 = kv * 4, m = r ^ sw;
      As[(k0 + 0) * 64 + m] = v.x;
      As[(k0 + 1) * 64 + m] = v.y;
      As[(k0 + 2) * 64 + m] = v.z;
      As[(k0 + 3) * 64 + m] = v.w;
    }
  }
  // stage W tile
  {
    int nv = tid & 15;            // float4 index along n
    int kb = tid >> 4;            // 0..15
#pragma unroll
    for (int it = 0; it < 8; ++it) {
      int k = it * 16 + kb;
      float4 v = *(const float4*)&W[(size_t)k * Ncols + bn + nv * 4];
      *(float4*)&Ws[k * 64 + nv * 4] = v;
    }
  }
  __syncthreads();

  const int m0 = (tid & 15) * 4;
  const int n0 = (tid >> 4) * 4;
  float acc[4][4] = {};
#pragma unroll 8
  for (int k = 0; k < 128; ++k) {
    int sw = ((k >> 2) & 7) << 2;
    float4 a = *(const float4*)&As[k * 64 + (m0 ^ sw)];
    float4 b = *(const float4*)&Ws[k * 64 + n0];
    acc[0][0] += a.x * b.x; acc[0][1] += a.x * b.y; acc[0][2] += a.x * b.z; acc[0][3] += a.x * b.w;
    acc[1][0] += a.y * b.x; acc[1][1] += a.y * b.y; acc[1][2] += a.y * b.z; acc[1][3] += a.y * b.w;
    acc[2][0] += a.z * b.x; acc[2][1] += a.z * b.y; acc[2][2] += a.z * b.z; acc[2][3] += a.z * b.w;
    acc[3][0] += a.w * b.x; acc[3][1] += a.w * b.y; acc[3][2] += a.w * b.z; acc[3][3] += a.w * b.w;
  }

#pragma unroll
  for (int i = 0; i < 4; ++i) {
    size_t off = (size_t)(bm + m0 + i) * Ncols + bn + n0;
#pragma unroll
    for (int j = 0; j < 4; ++j) {
      float v = acc[i][j];
      if (bias) v += bias[bn + n0 + j];
      if (act) v = 0.5f * v * (1.0f + erff(v * 0.70710678118654752f));
      if (resid) v += resid[off + j];
      C[off + j] = v;
    }
  }
}

// ---------- GroupNorm(8 groups of 16) + AdaGN modulate ----------
__global__ __launch_bounds__(256) void k_gn(const float* __restrict__ h_source,
                                            const float* __restrict__ style,
                                            const float* __restrict__ gn_gamma,
                                            const float* __restrict__ gn_beta,
                                            float* __restrict__ hmod, int total) {
  int gid = blockIdx.x * 256 + threadIdx.x;
  if (gid >= total) return;
  int n = gid >> 7, c = gid & 127;
  float x = h_source[gid];
  float s = x, q = x * x;
#pragma unroll
  for (int m = 8; m >= 1; m >>= 1) {
    s += __shfl_xor(s, m, 16);
    q += __shfl_xor(q, m, 16);
  }
  float mu = s * (1.0f / 16.0f);
  float var = q * (1.0f / 16.0f) - mu * mu;
  float nv = (x - mu) * rsqrtf(var + 1e-5f);
  nv = nv * gn_gamma[c] + gn_beta[c];
  float g = style[(size_t)n * 256 + c];
  float b = style[(size_t)n * 256 + 128 + c];
  hmod[gid] = nv * (1.0f + g) + b;
}

// ---------- edge pass A: logits + atomic max ----------
__global__ __launch_bounds__(256) void pass_a(const int* __restrict__ esrc,
                                              const int* __restrict__ edst,
                                              const float* __restrict__ pos,
                                              const float* __restrict__ nodeF,
                                              const float* __restrict__ att,
                                              float* __restrict__ logitb,
                                              unsigned* __restrict__ mkey, int E) {
  __shared__ float att_s[128];
  int tid = threadIdx.x;
  if (tid < 128) att_s[tid] = att[tid];
  __syncthreads();
  int e = blockIdx.x * 8 + (tid >> 5);
  if (e >= E) return;
  int lane = tid & 31;
  int src = esrc[e], dst = edst[e];
  float dx = pos[2 * src] - pos[2 * dst];
  float dy = pos[2 * src + 1] - pos[2 * dst + 1];
  float d2 = fmaxf(dx * dx + dy * dy, 1e-8f);
  float sy = -dy / d2, sx = dx / d2;
  size_t bs = (size_t)src * 512, bd = (size_t)dst * 512;
  float L[4];
#pragma unroll
  for (int h = 0; h < 4; ++h) {
    int c = h * 32 + lane;
    float xl = nodeF[bs + c];
    float xr = nodeF[bd + 128 + c];
    float ea = nodeF[bs + 256 + c] - nodeF[bd + 256 + c];
    float eb = nodeF[bs + 384 + c] - nodeF[bd + 384 + c];
    float z = xl + xr + sy * ea + sx * eb;
    z = (z > 0.0f) ? z : 0.2f * z;
    float p = att_s[c] * z;
#pragma unroll
    for (int mm = 16; mm >= 1; mm >>= 1) p += __shfl_xor(p, mm, 32);
    L[h] = p;
  }
  if (lane < 4) {
    float v = (lane == 0) ? L[0] : (lane == 1) ? L[1] : (lane == 2) ? L[2] : L[3];
    logitb[(size_t)e * 4 + lane] = v;
    atomicMax(&mkey[(size_t)dst * 4 + lane], ordkey(v));
  }
}

// ---------- edge pass B: ex = exp(logit - m) in-place, denom atomicAdd ----------
__global__ __launch_bounds__(256) void pass_b(const int* __restrict__ edst,
                                              float* __restrict__ logit_ex,
                                              const unsigned* __restrict__ mkey,
                                              float* __restrict__ denom, int total) {
  int idx = blockIdx.x * 256 + threadIdx.x;
  if (idx >= total) return;
  int e = idx >> 2, h = idx & 3;
  int dst = edst[e];
  unsigned key = mkey[dst * 4 + h];
  float m = (key == 0u) ? 0.0f : unordkey(key);
  float ex = expf(logit_ex[idx] - m);
  logit_ex[idx] = ex;
  atomicAdd(&denom[dst * 4 + h], ex);
}

// ---------- edge pass C: aggr += xl[src] * alpha ----------
__global__ __launch_bounds__(256) void pass_c(const int* __restrict__ esrc,
                                              const int* __restrict__ edst,
                                              const float* __restrict__ nodeF,
                                              const float* __restrict__ exb,
                                              const float* __restrict__ denom,
                                              float* __restrict__ aggr, int E) {
  int tid = threadIdx.x;
  int e = blockIdx.x * 8 + (tid >> 5);
  if (e >= E) return;
  int lane = tid & 31;
  int src = esrc[e], dst = edst[e];
  float al[4];
#pragma unroll
  for (int h = 0; h < 4; ++h)
    al[h] = exb[(size_t)e * 4 + h] / (denom[dst * 4 + h] + 1e-16f);
#pragma unroll
  for (int h = 0; h < 4; ++h) {
    int c = h * 32 + lane;
    atomicAdd(&aggr[(size_t)dst * 128 + c], nodeF[(size_t)src * 512 + c] * al[h]);
  }
}

// ---------- LayerNorm over 128 ----------
__global__ __launch_bounds__(256) void k_ln(const float* __restrict__ y,
                                            const float* __restrict__ ln_g,
                                            const float* __restrict__ ln_b,
                                            float* __restrict__ out, int N) {
  int node = blockIdx.x * 4 + (threadIdx.x >> 6);
  if (node >= N) return;
  int lane = threadIdx.x & 63;
  size_t base = (size_t)node * 128;
  float y1 = y[base + lane], y2 = y[base + 64 + lane];
  float s = y1 + y2, q = y1 * y1 + y2 * y2;
#pragma unroll
  for (int m = 32; m >= 1; m >>= 1) {
    s += __shfl_xor(s, m, 64);
    q += __shfl_xor(q, m, 64);
  }
  float mu = s * (1.0f / 128.0f);
  float var = q * (1.0f / 128.0f) - mu * mu;
  float r = rsqrtf(var + 1e-5f);
  out[base + lane] = (y1 - mu) * r * ln_g[lane] + ln_b[lane];
  out[base + 64 + lane] = (y2 - mu) * r * ln_g[lane + 64] + ln_b[lane + 64];
}

extern "C" void kernel_launch(void* const* d_in, const int* in_sizes, int n_in,
                              void* d_out, int out_size, void* d_ws, size_t ws_size,
                              hipStream_t stream) {
  const float* h_target = (const float*)d_in[0];
  const float* h_source = (const float*)d_in[1];
  const float* pos      = (const float*)d_in[2];
  const float* t_emb    = (const float*)d_in[3];
  const int*   eidx     = (const int*)d_in[4];
  const float* gn_gamma = (const float*)d_in[5];
  const float* gn_beta  = (const float*)d_in[6];
  const float* fc_W     = (const float*)d_in[7];
  const float* fc_b     = (const float*)d_in[8];
  const float* Wl       = (const float*)d_in[9];
  const float* bl       = (const float*)d_in[10];
  const float* Wr       = (const float*)d_in[11];
  const float* br       = (const float*)d_in[12];
  const float* We       = (const float*)d_in[13];
  const float* att      = (const float*)d_in[14];
  const float* gat_bias = (const float*)d_in[15];
  const float* Wpost    = (const float*)d_in[16];
  const float* bpost    = (const float*)d_in[17];
  const float* ln_g     = (const float*)d_in[18];
  const float* ln_b     = (const float*)d_in[19];
  const float* W1       = (const float*)d_in[20];
  const float* b1       = (const float*)d_in[21];
  const float* W2       = (const float*)d_in[22];
  const float* b2       = (const float*)d_in[23];

  const int N = in_sizes[0] / HID;     // 32768
  const int E = in_sizes[4] / 2;       // 524288
  const int* esrc = eidx;
  const int* edst = eidx + E;

  // ---- workspace layout (float offsets) ----
  float* ws = (float*)d_ws;
  const size_t MF = 1024 * 1024;
  float* style  = ws;                          // N*256 (32MB), dead after k_gn
  float* nodeF  = ws;                          // N*512 (64MB), overlaps style
  float* yb     = ws;                          // N*128, reuses nodeF region after pass_c
  float* lnb    = ws + 4 * MF;                 // N*128
  float* ub     = ws + 8 * MF;                 // N*128
  float* hmod   = ws + 16 * MF;                // N*128 (16MB)
  float* aggr   = hmod;                        // reuses hmod region after gemm2
  float* logitb = ws + 20 * MF;                // E*4 (8MB), becomes ex in-place
  unsigned* mkey = (unsigned*)(ws + 22 * MF);  // N*4 (512KB)
  float* denom  = ws + 22 * MF + 131072;       // N*4 (512KB)
  float* Wcat   = ws + 22 * MF + 262144;       // 128*512
  float* bcat   = Wcat + 65536;                // 512
  float* bpost2 = bcat + 512;                  // 128
  const size_t needed = (size_t)(22 * MF + 262144 + 65536 + 512 + 128) * 4;
  if (ws_size < needed) return;  // visible failure (out stays poisoned)

  dim3 blk(256);

  // 1. prep
  prep_kernel<<<258, blk, 0, stream>>>(Wl, bl, Wr, br, We, gat_bias, Wpost, bpost,
                                       Wcat, bcat, bpost2);
  // 2. style = t_emb @ fc_W + fc_b   [N x 256]
  gemm128<<<dim3(256 / 64, N / 64), blk, 0, stream>>>(t_emb, fc_W, fc_b, nullptr, style, 256, 0);
  // 3. GroupNorm + modulate -> hmod
  k_gn<<<(N * 128) / 256, blk, 0, stream>>>(h_source, style, gn_gamma, gn_beta, hmod, N * 128);
  // 4. nodeF = hmod @ Wcat + bcat    [N x 512] = [xl | xr | A | B]
  gemm128<<<dim3(512 / 64, N / 64), blk, 0, stream>>>(hmod, Wcat, bcat, nullptr, nodeF, 512, 0);
  // 5. zero accumulators (after gemm2: aggr aliases hmod)
  hipMemsetAsync(aggr, 0, (size_t)N * 128 * 4, stream);
  hipMemsetAsync(mkey, 0, (size_t)N * 4 * 4 * 2, stream);  // mkey + denom (contiguous 1MB)
  // 6. edge pass A: logits + max
  pass_a<<<E / 8, blk, 0, stream>>>(esrc, edst, pos, nodeF, att, logitb, mkey, E);
  // 7. edge pass B: exp + denom
  pass_b<<<(E * 4) / 256, blk, 0, stream>>>(edst, logitb, mkey, denom, E * 4);
  // 8. edge pass C: weighted aggregation
  pass_c<<<E / 8, blk, 0, stream>>>(esrc, edst, nodeF, logitb, denom, aggr, E);
  // 9. y = aggr @ Wpost + (bpost + gat_bias@Wpost)   [N x 128]
  gemm128<<<dim3(2, N / 64), blk, 0, stream>>>(aggr, Wpost, bpost2, nullptr, yb, 128, 0);
  // 10. LayerNorm
  k_ln<<<N / 4, blk, 0, stream>>>(yb, ln_g, ln_b, lnb, N);
  // 11. u = gelu(ln @ W1 + b1)
  gemm128<<<dim3(2, N / 64), blk, 0, stream>>>(lnb, W1, b1, nullptr, ub, 128, 1);
  // 12. out = u @ W2 + b2 + h_target
  gemm128<<<dim3(2, N / 64), blk, 0, stream>>>(ub, W2, b2, h_target, (float*)d_out, 128, 0);
}

// Round 2
// 536.079 us; speedup vs baseline: 1.5678x; 1.5678x over previous
//
#include <hip/hip_runtime.h>
#include <hip/hip_bf16.h>
#include <math.h>

#define HID 128

// ---------- prep: Wcat[128x512] = [Wl | Wr | We_top | We_bot], bcat, bpost2 ----------
__global__ void prep_kernel(const float* __restrict__ Wl, const float* __restrict__ bl,
                            const float* __restrict__ Wr, const float* __restrict__ br,
                            const float* __restrict__ We, const float* __restrict__ gat_bias,
                            const float* __restrict__ Wpost, const float* __restrict__ bpost,
                            float* __restrict__ Wcat, float* __restrict__ bcat,
                            float* __restrict__ bpost2) {
  int b = blockIdx.x, t = threadIdx.x;
  if (b < 256) {
    int id = b * 256 + t;           // 0..65535
    int k = id >> 9, j = id & 511;
    float v;
    if (j < 128)      v = Wl[k * 128 + j];
    else if (j < 256) v = Wr[k * 128 + (j - 128)];
    else if (j < 384) v = We[k * 128 + (j - 256)];
    else              v = We[(128 + k) * 128 + (j - 384)];
    Wcat[id] = v;
  } else if (b == 256) {
    for (int j = t; j < 512; j += 256)
      bcat[j] = (j < 128) ? bl[j] : (j < 256) ? br[j - 128] : 0.0f;
  } else {
    if (t < 128) {
      float s = bpost[t];
      for (int k = 0; k < 128; ++k) s += gat_bias[k] * Wpost[k * 128 + t];
      bpost2[t] = s;
    }
  }
}

// ---------- generic fp32 GEMM: C[M x Nc] = A[M x 128] @ W[128 x Nc] ----------
// mode: 0 = fp32 out, 1 = fp32 out + gelu, 2 = bf16 out
__global__ __launch_bounds__(256) void gemm128(const float* __restrict__ A,
                                               const float* __restrict__ W,
                                               const float* __restrict__ bias,
                                               const float* __restrict__ resid,
                                               void* __restrict__ Cv, int Ncols, int mode) {
  __shared__ float As[128 * 64];   // [k][m], XOR-swizzled on m
  __shared__ float Ws[128 * 64];   // [k][n]
  const int tid = threadIdx.x;
  const int bm = blockIdx.y * 64;
  const int bn = blockIdx.x * 64;

  {
    int kv = tid & 31;            // float4 index along k
    int rb = tid >> 5;            // 0..7
    int sw = (kv & 7) << 2;
#pragma unroll
    for (int it = 0; it < 8; ++it) {
      int r = it * 8 + rb;
      float4 v = *(const float4*)&A[(size_t)(bm + r) * 128 + kv * 4];
      int k0 = kv * 4, m = r ^ sw;
      As[(k0 + 0) * 64 + m] = v.x;
      As[(k0 + 1) * 64 + m] = v.y;
      As[(k0 + 2) * 64 + m] = v.z;
      As[(k0 + 3) * 64 + m] = v.w;
    }
  }
  {
    int nv = tid & 15;            // float4 index along n
    int kb = tid >> 4;            // 0..15
#pragma unroll
    for (int it = 0; it < 8; ++it) {
      int k = it * 16 + kb;
      float4 v = *(const float4*)&W[(size_t)k * Ncols + bn + nv * 4];
      *(float4*)&Ws[k * 64 + nv * 4] = v;
    }
  }
  __syncthreads();

  const int m0 = (tid & 15) * 4;
  const int n0 = (tid >> 4) * 4;
  float acc[4][4] = {};
#pragma unroll 8
  for (int k = 0; k < 128; ++k) {
    int sw = ((k >> 2) & 7) << 2;
    float4 a = *(const float4*)&As[k * 64 + (m0 ^ sw)];
    float4 b = *(const float4*)&Ws[k * 64 + n0];
    acc[0][0] += a.x * b.x; acc[0][1] += a.x * b.y; acc[0][2] += a.x * b.z; acc[0][3] += a.x * b.w;
    acc[1][0] += a.y * b.x; acc[1][1] += a.y * b.y; acc[1][2] += a.y * b.z; acc[1][3] += a.y * b.w;
    acc[2][0] += a.z * b.x; acc[2][1] += a.z * b.y; acc[2][2] += a.z * b.z; acc[2][3] += a.z * b.w;
    acc[3][0] += a.w * b.x; acc[3][1] += a.w * b.y; acc[3][2] += a.w * b.z; acc[3][3] += a.w * b.w;
  }

#pragma unroll
  for (int i = 0; i < 4; ++i) {
    size_t off = (size_t)(bm + m0 + i) * Ncols + bn + n0;
#pragma unroll
    for (int j = 0; j < 4; ++j) {
      float v = acc[i][j];
      if (bias) v += bias[bn + n0 + j];
      if (mode == 1) v = 0.5f * v * (1.0f + erff(v * 0.70710678118654752f));
      if (resid) v += resid[off + j];
      if (mode == 2) ((__hip_bfloat16*)Cv)[off + j] = __float2bfloat16(v);
      else           ((float*)Cv)[off + j] = v;
    }
  }
}

// ---------- GroupNorm(8 groups of 16) + AdaGN modulate ----------
__global__ __launch_bounds__(256) void k_gn(const float* __restrict__ h_source,
                                            const float* __restrict__ style,
                                            const float* __restrict__ gn_gamma,
                                            const float* __restrict__ gn_beta,
                                            float* __restrict__ hmod, int total) {
  int gid = blockIdx.x * 256 + threadIdx.x;
  if (gid >= total) return;
  int n = gid >> 7, c = gid & 127;
  float x = h_source[gid];
  float s = x, q = x * x;
#pragma unroll
  for (int m = 8; m >= 1; m >>= 1) {
    s += __shfl_xor(s, m, 16);
    q += __shfl_xor(q, m, 16);
  }
  float mu = s * (1.0f / 16.0f);
  float var = q * (1.0f / 16.0f) - mu * mu;
  float nv = (x - mu) * rsqrtf(var + 1e-5f);
  nv = nv * gn_gamma[c] + gn_beta[c];
  float g = style[(size_t)n * 256 + c];
  float b = style[(size_t)n * 256 + 128 + c];
  hmod[gid] = nv * (1.0f + g) + b;
}

// ---------- CSR build ----------
__global__ __launch_bounds__(256) void k_hist(const int* __restrict__ edst,
                                              int* __restrict__ count, int E) {
  int e = blockIdx.x * 256 + threadIdx.x;
  if (e < E) atomicAdd(&count[edst[e]], 1);
}

__global__ __launch_bounds__(1024) void k_scan(const int* __restrict__ count,
                                               int* __restrict__ rowptr,
                                               int* __restrict__ cursor, int N, int E) {
  __shared__ int part[1024];
  int t = threadIdx.x;
  int base = t * 32;
  int local[32];
  int s = 0;
#pragma unroll
  for (int i = 0; i < 32; ++i) { local[i] = count[base + i]; s += local[i]; }
  part[t] = s;
  __syncthreads();
  for (int off = 1; off < 1024; off <<= 1) {
    int v = part[t];
    int addv = (t >= off) ? part[t - off] : 0;
    __syncthreads();
    part[t] = v + addv;
    __syncthreads();
  }
  int run = (t == 0) ? 0 : part[t - 1];
#pragma unroll
  for (int i = 0; i < 32; ++i) {
    rowptr[base + i] = run;
    cursor[base + i] = run;
    run += local[i];
  }
  if (t == 1023) rowptr[N] = E;
}

__global__ __launch_bounds__(256) void k_scatter(const int* __restrict__ esrc,
                                                 const int* __restrict__ edst,
                                                 const float* __restrict__ pos,
                                                 int* __restrict__ cursor,
                                                 int* __restrict__ ssrc,
                                                 float* __restrict__ ssy,
                                                 float* __restrict__ ssx, int E) {
  int e = blockIdx.x * 256 + threadIdx.x;
  if (e >= E) return;
  int src = esrc[e], dst = edst[e];
  int p = atomicAdd(&cursor[dst], 1);
  float dx = pos[2 * src] - pos[2 * dst];
  float dy = pos[2 * src + 1] - pos[2 * dst + 1];
  float d2 = fmaxf(dx * dx + dy * dy, 1e-8f);
  ssrc[p] = src;
  ssy[p] = -dy / d2;
  ssx[p] = dx / d2;
}

// ---------- fused edge kernel: logit + online softmax + aggregate, per dst node ----------
// nodeF16[N x 512] bf16 = [xl | xr | A | B]. One wave per dst node, lane -> 2 channels.
__device__ __forceinline__ void ld2bf(const __hip_bfloat16* p, float& x, float& y) {
  __hip_bfloat162 v = *(const __hip_bfloat162*)p;
  x = __bfloat162float(v.x);
  y = __bfloat162float(v.y);
}

__global__ __launch_bounds__(256) void k_edge(const int* __restrict__ rowptr,
                                              const int* __restrict__ ssrc,
                                              const float* __restrict__ ssy,
                                              const float* __restrict__ ssx,
                                              const __hip_bfloat16* __restrict__ nodeF,
                                              const float* __restrict__ att,
                                              float* __restrict__ aggr, int N) {
  __shared__ float att_s[128];
  int tid = threadIdx.x;
  if (tid < 128) att_s[tid] = att[tid];
  __syncthreads();
  int d = blockIdx.x * 4 + (tid >> 6);
  if (d >= N) return;
  int lane = tid & 63;
  int c0 = lane * 2;
  float a0 = att_s[c0], a1 = att_s[c0 + 1];
  size_t nb = (size_t)d * 512;
  float xr0, xr1, Ad0, Ad1, Bd0, Bd1;
  ld2bf(nodeF + nb + 128 + c0, xr0, xr1);
  ld2bf(nodeF + nb + 256 + c0, Ad0, Ad1);
  ld2bf(nodeF + nb + 384 + c0, Bd0, Bd1);

  int beg = rowptr[d], end = rowptr[d + 1];
  float m = -INFINITY, lsum = 0.0f, acc0 = 0.0f, acc1 = 0.0f;
  for (int j = beg; j < end; ++j) {
    int s = ssrc[j];
    float sy = ssy[j], sx = ssx[j];
    size_t sb = (size_t)s * 512;
    float xl0, xl1, A0, A1, B0, B1;
    ld2bf(nodeF + sb + c0, xl0, xl1);
    ld2bf(nodeF + sb + 256 + c0, A0, A1);
    ld2bf(nodeF + sb + 384 + c0, B0, B1);
    float z0 = xl0 + xr0 + sy * (A0 - Ad0) + sx * (B0 - Bd0);
    float z1 = xl1 + xr1 + sy * (A1 - Ad1) + sx * (B1 - Bd1);
    z0 = (z0 > 0.0f) ? z0 : 0.2f * z0;
    z1 = (z1 > 0.0f) ? z1 : 0.2f * z1;
    float p = a0 * z0 + a1 * z1;
#pragma unroll
    for (int mm = 8; mm >= 1; mm >>= 1) p += __shfl_xor(p, mm);
    // online softmax update (head-uniform across the 16-lane group)
    float nm = fmaxf(m, p);
    float sc = expf(m - nm);       // first iter: exp(-inf) = 0
    float ex = expf(p - nm);
    lsum = lsum * sc + ex;
    acc0 = acc0 * sc + ex * xl0;
    acc1 = acc1 * sc + ex * xl1;
    m = nm;
  }
  float inv = 1.0f / (lsum + 1e-16f);
  float2 o = make_float2(acc0 * inv, acc1 * inv);
  *(float2*)&aggr[(size_t)d * 128 + c0] = o;
}

// ---------- LayerNorm over 128 ----------
__global__ __launch_bounds__(256) void k_ln(const float* __restrict__ y,
                                            const float* __restrict__ ln_g,
                                            const float* __restrict__ ln_b,
                                            float* __restrict__ out, int N) {
  int node = blockIdx.x * 4 + (threadIdx.x >> 6);
  if (node >= N) return;
  int lane = threadIdx.x & 63;
  size_t base = (size_t)node * 128;
  float y1 = y[base + lane], y2 = y[base + 64 + lane];
  float s = y1 + y2, q = y1 * y1 + y2 * y2;
#pragma unroll
  for (int m = 32; m >= 1; m >>= 1) {
    s += __shfl_xor(s, m, 64);
    q += __shfl_xor(q, m, 64);
  }
  float mu = s * (1.0f / 128.0f);
  float var = q * (1.0f / 128.0f) - mu * mu;
  float r = rsqrtf(var + 1e-5f);
  out[base + lane] = (y1 - mu) * r * ln_g[lane] + ln_b[lane];
  out[base + 64 + lane] = (y2 - mu) * r * ln_g[lane + 64] + ln_b[lane + 64];
}

extern "C" void kernel_launch(void* const* d_in, const int* in_sizes, int n_in,
                              void* d_out, int out_size, void* d_ws, size_t ws_size,
                              hipStream_t stream) {
  const float* h_target = (const float*)d_in[0];
  const float* h_source = (const float*)d_in[1];
  const float* pos      = (const float*)d_in[2];
  const float* t_emb    = (const float*)d_in[3];
  const int*   eidx     = (const int*)d_in[4];
  const float* gn_gamma = (const float*)d_in[5];
  const float* gn_beta  = (const float*)d_in[6];
  const float* fc_W     = (const float*)d_in[7];
  const float* fc_b     = (const float*)d_in[8];
  const float* Wl       = (const float*)d_in[9];
  const float* bl       = (const float*)d_in[10];
  const float* Wr       = (const float*)d_in[11];
  const float* br       = (const float*)d_in[12];
  const float* We       = (const float*)d_in[13];
  const float* att      = (const float*)d_in[14];
  const float* gat_bias = (const float*)d_in[15];
  const float* Wpost    = (const float*)d_in[16];
  const float* bpost    = (const float*)d_in[17];
  const float* ln_g     = (const float*)d_in[18];
  const float* ln_b     = (const float*)d_in[19];
  const float* W1       = (const float*)d_in[20];
  const float* b1       = (const float*)d_in[21];
  const float* W2       = (const float*)d_in[22];
  const float* b2       = (const float*)d_in[23];

  const int N = in_sizes[0] / HID;     // 32768
  const int E = in_sizes[4] / 2;       // 524288
  const int* esrc = eidx;
  const int* edst = eidx + E;

  // ---- workspace layout (float offsets; MF = 1M floats = 4MB) ----
  // R0 [0,8MF):   style (fp32 8MF) -> nodeF16 (bf16, 16M elems = 8MF bytes-area) -> ub [0,4MF)
  // R1 [8,12MF):  hmod -> aggr
  // R2 [12,16MF): edge meta (ssrc/ssy/ssx/rowptr/count/cursor; dead after k_edge) -> yb
  // R3 [16,20MF): lnb
  // [20MF,..):    Wcat/bcat/bpost2
  float* ws = (float*)d_ws;
  const size_t MF = 1024 * 1024;
  float* style  = ws;
  __hip_bfloat16* nodeF16 = (__hip_bfloat16*)ws;
  float* ub     = ws;
  float* hmod   = ws + 8 * MF;
  float* aggr   = hmod;
  float* yb     = ws + 12 * MF;
  int*   ssrc_s = (int*)(ws + 12 * MF);
  float* ssy_s  = ws + 12 * MF + 524288;
  float* ssx_s  = ws + 13 * MF;
  int*   rowptr = (int*)(ws + 13 * MF + 524288);
  int*   count  = (int*)(ws + 13 * MF + 524288 + 40960);
  int*   cursor = (int*)(ws + 13 * MF + 524288 + 81920);
  float* lnb    = ws + 16 * MF;
  float* Wcat   = ws + 20 * MF;
  float* bcat   = Wcat + 65536;
  float* bpost2 = bcat + 512;
  const size_t needed = (size_t)(20 * MF + 66176) * 4;
  if (ws_size < needed) return;  // visible failure (out stays poisoned)

  dim3 blk(256);

  // 1. prep
  prep_kernel<<<258, blk, 0, stream>>>(Wl, bl, Wr, br, We, gat_bias, Wpost, bpost,
                                       Wcat, bcat, bpost2);
  // 2. style = t_emb @ fc_W + fc_b   [N x 256]
  gemm128<<<dim3(256 / 64, N / 64), blk, 0, stream>>>(t_emb, fc_W, fc_b, nullptr, style, 256, 0);
  // 3. GroupNorm + modulate -> hmod (R1)
  k_gn<<<(N * 128) / 256, blk, 0, stream>>>(h_source, style, gn_gamma, gn_beta, hmod, N * 128);
  // 4. nodeF16 = bf16(hmod @ Wcat + bcat)  [N x 512] = [xl | xr | A | B]  (overwrites style)
  gemm128<<<dim3(512 / 64, N / 64), blk, 0, stream>>>(hmod, Wcat, bcat, nullptr, nodeF16, 512, 2);
  // 5. CSR build
  hipMemsetAsync(count, 0, (size_t)N * 4, stream);
  k_hist<<<(E + 255) / 256, blk, 0, stream>>>(edst, count, E);
  k_scan<<<1, 1024, 0, stream>>>(count, rowptr, cursor, N, E);
  k_scatter<<<(E + 255) / 256, blk, 0, stream>>>(esrc, edst, pos, cursor, ssrc_s, ssy_s, ssx_s, E);
  // 6. fused edge pass: logits + online softmax + aggregation -> aggr (overwrites hmod)
  k_edge<<<(N + 3) / 4, blk, 0, stream>>>(rowptr, ssrc_s, ssy_s, ssx_s, nodeF16, att, aggr, N);
  // 7. y = aggr @ Wpost + (bpost + gat_bias@Wpost)   [N x 128]  (meta now dead; yb takes R2)
  gemm128<<<dim3(2, N / 64), blk, 0, stream>>>(aggr, Wpost, bpost2, nullptr, yb, 128, 0);
  // 8. LayerNorm
  k_ln<<<N / 4, blk, 0, stream>>>(yb, ln_g, ln_b, lnb, N);
  // 9. u = gelu(ln @ W1 + b1)  -> ub (R0, nodeF16 dead)
  gemm128<<<dim3(2, N / 64), blk, 0, stream>>>(lnb, W1, b1, nullptr, ub, 128, 1);
  // 10. out = u @ W2 + b2 + h_target
  gemm128<<<dim3(2, N / 64), blk, 0, stream>>>(ub, W2, b2, h_target, (float*)d_out, 128, 0);
}

// Round 3
// 510.683 us; speedup vs baseline: 1.6457x; 1.0497x over previous
//
#include <hip/hip_runtime.h>
#include <hip/hip_bf16.h>
#include <math.h>

#define HID 128

typedef __bf16 bf16x8 __attribute__((ext_vector_type(8)));
typedef float f32x4 __attribute__((ext_vector_type(4)));
union BF8 { uint4 u; bf16x8 v; unsigned short s[8]; };

__device__ __forceinline__ unsigned short f2bf(float x) {
  unsigned u = __float_as_uint(x);
  unsigned r = u + 0x7FFFu + ((u >> 16) & 1u);   // RNE (finite inputs)
  return (unsigned short)(r >> 16);
}
__device__ __forceinline__ float bf2f(unsigned short h) {
  return __uint_as_float(((unsigned)h) << 16);
}
__device__ __forceinline__ void ld2bf(const unsigned short* p, float& x, float& y) {
  unsigned v = *(const unsigned*)p;
  x = __uint_as_float((v & 0xFFFFu) << 16);
  y = __uint_as_float(v & 0xFFFF0000u);
}

// ---------- prep: transposed (and hi/lo split) weights ----------
__global__ void prep2(const float* __restrict__ fc_W, const float* __restrict__ Wl,
                      const float* __restrict__ Wr, const float* __restrict__ We,
                      const float* __restrict__ Wpost, const float* __restrict__ W1,
                      const float* __restrict__ W2, const float* __restrict__ bl,
                      const float* __restrict__ br, const float* __restrict__ gat_bias,
                      const float* __restrict__ bpost,
                      unsigned short* __restrict__ fcTh, unsigned short* __restrict__ fcTl,
                      unsigned short* __restrict__ WxyT, unsigned short* __restrict__ WeTh,
                      unsigned short* __restrict__ WeTl, unsigned short* __restrict__ WpT,
                      unsigned short* __restrict__ W1T, unsigned short* __restrict__ W2T,
                      float* __restrict__ bxy, float* __restrict__ bpost2) {
  int gid = blockIdx.x * 256 + threadIdx.x;
  if (gid < 32768) {                       // fc_W [128x256] -> fcT hi/lo [256][128]
    int n = gid >> 7, k = gid & 127;
    float x = fc_W[k * 256 + n];
    unsigned short h = f2bf(x);
    fcTh[n * 128 + k] = h;
    fcTl[n * 128 + k] = f2bf(x - bf2f(h));
  } else if (gid < 65536) {                // [Wl|Wr] -> WxyT [256][128]
    int i = gid - 32768; int n = i >> 7, k = i & 127;
    float x = (n < 128) ? Wl[k * 128 + n] : Wr[k * 128 + (n - 128)];
    WxyT[n * 128 + k] = f2bf(x);
  } else if (gid < 98304) {                // We -> WeT hi/lo [256][128]
    int i = gid - 65536; int n = i >> 7, k = i & 127;
    float x = (n < 128) ? We[k * 128 + n] : We[(128 + k) * 128 + (n - 128)];
    unsigned short h = f2bf(x);
    WeTh[n * 128 + k] = h;
    WeTl[n * 128 + k] = f2bf(x - bf2f(h));
  } else if (gid < 147456) {               // Wpost/W1/W2 -> T [128][128]
    int i = gid - 98304; int which = i >> 14; int j = i & 16383;
    int n = j >> 7, k = j & 127;
    const float* W = (which == 0) ? Wpost : (which == 1) ? W1 : W2;
    unsigned short* T = (which == 0) ? WpT : (which == 1) ? W1T : W2T;
    T[n * 128 + k] = f2bf(W[k * 128 + n]);
  } else if (gid < 147712) {               // bxy = [bl|br]
    int j = gid - 147456;
    bxy[j] = (j < 128) ? bl[j] : br[j - 128];
  } else if (gid < 147840) {               // bpost2 = bpost + gat_bias @ Wpost
    int t = gid - 147712;
    float s = bpost[t];
    for (int k = 0; k < 128; ++k) s += gat_bias[k] * Wpost[k * 128 + t];
    bpost2[t] = s;
  }
}

// ---------- MFMA GEMM: C[M x Ncols] = A[M x 128] @ WT^T (+bias)(gelu)(resid) ----------
// WT layout [Ncols][128] bf16 (hi; lo optional for split precision).
// grid M/64 blocks x 256 thr; wave handles 16 rows, sweeps all n-tiles.
// mode: 0 fp32 out, 1 fp32+gelu, 2 bf16 out
__global__ __launch_bounds__(256) void gemm_mfma(const float* __restrict__ A,
                                                 const unsigned short* __restrict__ WTh,
                                                 const unsigned short* __restrict__ WTl,
                                                 const float* __restrict__ bias,
                                                 const float* __restrict__ resid,
                                                 void* __restrict__ Cv, int Ncols, int mode) {
  int tid = threadIdx.x;
  int wave = tid >> 6, lane = tid & 63;
  int m = lane & 15, q = lane >> 4;
  int r0 = blockIdx.x * 64 + wave * 16;
  const bool split = (WTl != nullptr);
  const float* arow = A + (size_t)(r0 + m) * 128 + q * 8;
  BF8 Ah[4], Al[4];
#pragma unroll
  for (int kc = 0; kc < 4; ++kc) {
    float4 x0 = *(const float4*)(arow + kc * 32);
    float4 x1 = *(const float4*)(arow + kc * 32 + 4);
    float xs[8] = {x0.x, x0.y, x0.z, x0.w, x1.x, x1.y, x1.z, x1.w};
#pragma unroll
    for (int j = 0; j < 8; ++j) {
      unsigned short h = f2bf(xs[j]);
      Ah[kc].s[j] = h;
      Al[kc].s[j] = split ? f2bf(xs[j] - bf2f(h)) : (unsigned short)0;
    }
  }
  int ntiles = Ncols >> 4;
  for (int nt = 0; nt < ntiles; ++nt) {
    const unsigned short* wr = WTh + (size_t)(nt * 16 + m) * 128 + q * 8;
    f32x4 acc = {0.f, 0.f, 0.f, 0.f};
    if (split) {
      const unsigned short* wrl = WTl + (size_t)(nt * 16 + m) * 128 + q * 8;
#pragma unroll
      for (int kc = 0; kc < 4; ++kc) {
        BF8 bh, blo;
        bh.u  = *(const uint4*)(wr + kc * 32);
        blo.u = *(const uint4*)(wrl + kc * 32);
        acc = __builtin_amdgcn_mfma_f32_16x16x32_bf16(Ah[kc].v, bh.v, acc, 0, 0, 0);
        acc = __builtin_amdgcn_mfma_f32_16x16x32_bf16(Al[kc].v, bh.v, acc, 0, 0, 0);
        acc = __builtin_amdgcn_mfma_f32_16x16x32_bf16(Ah[kc].v, blo.v, acc, 0, 0, 0);
      }
    } else {
#pragma unroll
      for (int kc = 0; kc < 4; ++kc) {
        BF8 bh;
        bh.u = *(const uint4*)(wr + kc * 32);
        acc = __builtin_amdgcn_mfma_f32_16x16x32_bf16(Ah[kc].v, bh.v, acc, 0, 0, 0);
      }
    }
    int n = nt * 16 + m;
    float bv = bias ? bias[n] : 0.0f;
#pragma unroll
    for (int i = 0; i < 4; ++i) {
      int row = r0 + q * 4 + i;
      float v = acc[i] + bv;
      if (mode == 1) v = 0.5f * v * (1.0f + erff(v * 0.70710678118654752f));
      size_t off = (size_t)row * Ncols + n;
      if (resid) v += resid[off];
      if (mode == 2) ((unsigned short*)Cv)[off] = f2bf(v);
      else           ((float*)Cv)[off] = v;
    }
  }
}

// ---------- GroupNorm(8 groups of 16) + AdaGN modulate ----------
__global__ __launch_bounds__(256) void k_gn(const float* __restrict__ h_source,
                                            const float* __restrict__ style,
                                            const float* __restrict__ gn_gamma,
                                            const float* __restrict__ gn_beta,
                                            float* __restrict__ hmod, int total) {
  int gid = blockIdx.x * 256 + threadIdx.x;
  if (gid >= total) return;
  int n = gid >> 7, c = gid & 127;
  float x = h_source[gid];
  float s = x, q = x * x;
#pragma unroll
  for (int m = 8; m >= 1; m >>= 1) {
    s += __shfl_xor(s, m, 16);
    q += __shfl_xor(q, m, 16);
  }
  float mu = s * (1.0f / 16.0f);
  float var = q * (1.0f / 16.0f) - mu * mu;
  float nv = (x - mu) * rsqrtf(var + 1e-5f);
  nv = nv * gn_gamma[c] + gn_beta[c];
  float g = style[(size_t)n * 256 + c];
  float b = style[(size_t)n * 256 + 128 + c];
  hmod[gid] = nv * (1.0f + g) + b;
}

// ---------- CSR build ----------
__global__ __launch_bounds__(256) void k_hist(const int* __restrict__ edst,
                                              int* __restrict__ count, int E) {
  int e = blockIdx.x * 256 + threadIdx.x;
  if (e < E) atomicAdd(&count[edst[e]], 1);
}

__global__ __launch_bounds__(1024) void k_scan(const int* __restrict__ count,
                                               int* __restrict__ rowptr,
                                               int* __restrict__ cursor, int N, int E) {
  __shared__ int part[1024];
  int t = threadIdx.x;
  int base = t * 32;
  int local[32];
  int s = 0;
#pragma unroll
  for (int i = 0; i < 32; ++i) { local[i] = count[base + i]; s += local[i]; }
  part[t] = s;
  __syncthreads();
  for (int off = 1; off < 1024; off <<= 1) {
    int v = part[t];
    int addv = (t >= off) ? part[t - off] : 0;
    __syncthreads();
    part[t] = v + addv;
    __syncthreads();
  }
  int run = (t == 0) ? 0 : part[t - 1];
#pragma unroll
  for (int i = 0; i < 32; ++i) {
    rowptr[base + i] = run;
    cursor[base + i] = run;
    run += local[i];
  }
  if (t == 1023) rowptr[N] = E;
}

__global__ __launch_bounds__(256) void k_scatter(const int* __restrict__ esrc,
                                                 const int* __restrict__ edst,
                                                 const float* __restrict__ pos,
                                                 int* __restrict__ cursor,
                                                 int* __restrict__ ssrc,
                                                 float* __restrict__ ssy,
                                                 float* __restrict__ ssx, int E) {
  int e = blockIdx.x * 256 + threadIdx.x;
  if (e >= E) return;
  int src = esrc[e], dst = edst[e];
  int p = atomicAdd(&cursor[dst], 1);
  float dx = pos[2 * src] - pos[2 * dst];
  float dy = pos[2 * src + 1] - pos[2 * dst + 1];
  float d2 = fmaxf(dx * dx + dy * dy, 1e-8f);
  ssrc[p] = src;
  ssy[p] = -dy / d2;
  ssx[p] = dx / d2;
}

// ---------- fused edge: logit + online softmax + aggregate; one wave per dst ----------
// nodeF16 [N][256] bf16 = [xl|xr];  nodeG [N][256] fp32 = [A|B]
__global__ __launch_bounds__(256) void k_edge(const int* __restrict__ rowptr,
                                              const int* __restrict__ ssrc,
                                              const float* __restrict__ ssy,
                                              const float* __restrict__ ssx,
                                              const unsigned short* __restrict__ nodeF,
                                              const float* __restrict__ nodeG,
                                              const float* __restrict__ att,
                                              float* __restrict__ aggr, int N) {
  __shared__ float att_s[128];
  int tid = threadIdx.x;
  if (tid < 128) att_s[tid] = att[tid];
  __syncthreads();
  int d = blockIdx.x * 4 + (tid >> 6);
  if (d >= N) return;
  int lane = tid & 63;
  int c0 = lane * 2;
  float a0 = att_s[c0], a1 = att_s[c0 + 1];
  float xr0, xr1;
  ld2bf(nodeF + (size_t)d * 256 + 128 + c0, xr0, xr1);
  float2 Ad = *(const float2*)(nodeG + (size_t)d * 256 + c0);
  float2 Bd = *(const float2*)(nodeG + (size_t)d * 256 + 128 + c0);

  int beg = rowptr[d], end = rowptr[d + 1];
  float m = -INFINITY, lsum = 0.0f, acc0 = 0.0f, acc1 = 0.0f;
  for (int j = beg; j < end; ++j) {
    int s = ssrc[j];
    float sy = ssy[j], sx = ssx[j];
    float xl0, xl1;
    ld2bf(nodeF + (size_t)s * 256 + c0, xl0, xl1);
    float2 As = *(const float2*)(nodeG + (size_t)s * 256 + c0);
    float2 Bs = *(const float2*)(nodeG + (size_t)s * 256 + 128 + c0);
    float z0 = xl0 + xr0 + sy * (As.x - Ad.x) + sx * (Bs.x - Bd.x);
    float z1 = xl1 + xr1 + sy * (As.y - Ad.y) + sx * (Bs.y - Bd.y);
    z0 = (z0 > 0.0f) ? z0 : 0.2f * z0;
    z1 = (z1 > 0.0f) ? z1 : 0.2f * z1;
    float p = a0 * z0 + a1 * z1;
#pragma unroll
    for (int mm = 8; mm >= 1; mm >>= 1) p += __shfl_xor(p, mm);
    float nm = fmaxf(m, p);
    float sc = expf(m - nm);
    float ex = expf(p - nm);
    lsum = lsum * sc + ex;
    acc0 = acc0 * sc + ex * xl0;
    acc1 = acc1 * sc + ex * xl1;
    m = nm;
  }
  float inv = 1.0f / (lsum + 1e-16f);
  float2 o = make_float2(acc0 * inv, acc1 * inv);
  *(float2*)&aggr[(size_t)d * 128 + c0] = o;
}

// ---------- LayerNorm over 128 ----------
__global__ __launch_bounds__(256) void k_ln(const float* __restrict__ y,
                                            const float* __restrict__ ln_g,
                                            const float* __restrict__ ln_b,
                                            float* __restrict__ out, int N) {
  int node = blockIdx.x * 4 + (threadIdx.x >> 6);
  if (node >= N) return;
  int lane = threadIdx.x & 63;
  size_t base = (size_t)node * 128;
  float y1 = y[base + lane], y2 = y[base + 64 + lane];
  float s = y1 + y2, q = y1 * y1 + y2 * y2;
#pragma unroll
  for (int m = 32; m >= 1; m >>= 1) {
    s += __shfl_xor(s, m, 64);
    q += __shfl_xor(q, m, 64);
  }
  float mu = s * (1.0f / 128.0f);
  float var = q * (1.0f / 128.0f) - mu * mu;
  float r = rsqrtf(var + 1e-5f);
  out[base + lane] = (y1 - mu) * r * ln_g[lane] + ln_b[lane];
  out[base + 64 + lane] = (y2 - mu) * r * ln_g[lane + 64] + ln_b[lane + 64];
}

extern "C" void kernel_launch(void* const* d_in, const int* in_sizes, int n_in,
                              void* d_out, int out_size, void* d_ws, size_t ws_size,
                              hipStream_t stream) {
  const float* h_target = (const float*)d_in[0];
  const float* h_source = (const float*)d_in[1];
  const float* pos      = (const float*)d_in[2];
  const float* t_emb    = (const float*)d_in[3];
  const int*   eidx     = (const int*)d_in[4];
  const float* gn_gamma = (const float*)d_in[5];
  const float* gn_beta  = (const float*)d_in[6];
  const float* fc_W     = (const float*)d_in[7];
  const float* fc_b     = (const float*)d_in[8];
  const float* Wl       = (const float*)d_in[9];
  const float* bl       = (const float*)d_in[10];
  const float* Wr       = (const float*)d_in[11];
  const float* br       = (const float*)d_in[12];
  const float* We       = (const float*)d_in[13];
  const float* att      = (const float*)d_in[14];
  const float* gat_bias = (const float*)d_in[15];
  const float* Wpost    = (const float*)d_in[16];
  const float* bpost    = (const float*)d_in[17];
  const float* ln_g     = (const float*)d_in[18];
  const float* ln_b     = (const float*)d_in[19];
  const float* W1       = (const float*)d_in[20];
  const float* b1       = (const float*)d_in[21];
  const float* W2       = (const float*)d_in[22];
  const float* b2       = (const float*)d_in[23];

  const int N = in_sizes[0] / HID;     // 32768
  const int E = in_sizes[4] / 2;       // 524288
  const int* esrc = eidx;
  const int* edst = eidx + E;

  // ---- workspace (float offsets; MF = 1M floats = 4MB). Timeline-overlapped:
  // [0,8MF):  style -> nodeG (after k_gn) -> yb [0,4) + lnb [4,8) (after k_edge)
  // [8,12MF): hmod -> aggr
  // [12,16MF): nodeF16 (bf16) -> ub
  // [16,~17.6MF): edge meta    [18MF,..): weights
  float* ws = (float*)d_ws;
  const size_t MF = 1024 * 1024;
  float* style  = ws;
  float* nodeG  = ws;
  float* yb     = ws;
  float* lnb    = ws + 4 * MF;
  float* hmod   = ws + 8 * MF;
  float* aggr   = ws + 8 * MF;
  unsigned short* nodeF16 = (unsigned short*)(ws + 12 * MF);
  float* ub     = ws + 12 * MF;
  int*   ssrc_s = (int*)(ws + 16 * MF);
  float* ssy_s  = ws + 16 * MF + 524288;
  float* ssx_s  = ws + 17 * MF;
  int*   rowptr = (int*)(ws + 17 * MF + 524288);
  int*   count  = rowptr + 32832;
  int*   cursor = count + 32832;
  unsigned short* wgt = (unsigned short*)(ws + 18 * MF);
  unsigned short* fcTh = wgt;
  unsigned short* fcTl = wgt + 32768;
  unsigned short* WxyT = wgt + 65536;
  unsigned short* WeTh = wgt + 98304;
  unsigned short* WeTl = wgt + 131072;
  unsigned short* WpT  = wgt + 163840;
  unsigned short* W1T  = wgt + 180224;
  unsigned short* W2T  = wgt + 196608;
  float* bxy    = (float*)(wgt + 212992);
  float* bpost2 = bxy + 256;
  const size_t needed = (size_t)(18 * MF + 106496 + 512) * 4;
  if (ws_size < needed) return;  // visible failure (out stays poisoned)

  dim3 blk(256);
  const int GB = N / 64;  // 512 blocks for M=32768

  // 1. prep (transpose + hi/lo split weights, biases)
  prep2<<<578, blk, 0, stream>>>(fc_W, Wl, Wr, We, Wpost, W1, W2, bl, br, gat_bias, bpost,
                                 fcTh, fcTl, WxyT, WeTh, WeTl, WpT, W1T, W2T, bxy, bpost2);
  // 2. style = t_emb @ fc_W + fc_b  [N x 256]  (split precision)
  gemm_mfma<<<GB, blk, 0, stream>>>(t_emb, fcTh, fcTl, fc_b, nullptr, style, 256, 0);
  // 3. GroupNorm + modulate -> hmod
  k_gn<<<(N * 128) / 256, blk, 0, stream>>>(h_source, style, gn_gamma, gn_beta, hmod, N * 128);
  // 4a. nodeF16 = bf16(hmod @ [Wl|Wr] + [bl|br])  [N x 256]  (plain)
  gemm_mfma<<<GB, blk, 0, stream>>>(hmod, WxyT, nullptr, bxy, nullptr, nodeF16, 256, 2);
  // 4b. nodeG = hmod @ [We_top|We_bot]  [N x 256] fp32  (split precision)
  gemm_mfma<<<GB, blk, 0, stream>>>(hmod, WeTh, WeTl, nullptr, nullptr, nodeG, 256, 0);
  // 5. CSR build
  hipMemsetAsync(count, 0, (size_t)N * 4, stream);
  k_hist<<<(E + 255) / 256, blk, 0, stream>>>(edst, count, E);
  k_scan<<<1, 1024, 0, stream>>>(count, rowptr, cursor, N, E);
  k_scatter<<<(E + 255) / 256, blk, 0, stream>>>(esrc, edst, pos, cursor, ssrc_s, ssy_s, ssx_s, E);
  // 6. fused edge pass -> aggr
  k_edge<<<(N + 3) / 4, blk, 0, stream>>>(rowptr, ssrc_s, ssy_s, ssx_s, nodeF16, nodeG, att, aggr, N);
  // 7. yb = aggr @ Wpost + bpost2
  gemm_mfma<<<GB, blk, 0, stream>>>(aggr, WpT, nullptr, bpost2, nullptr, yb, 128, 0);
  // 8. LayerNorm
  k_ln<<<N / 4, blk, 0, stream>>>(yb, ln_g, ln_b, lnb, N);
  // 9. ub = gelu(lnb @ W1 + b1)
  gemm_mfma<<<GB, blk, 0, stream>>>(lnb, W1T, nullptr, b1, nullptr, ub, 128, 1);
  // 10. out = ub @ W2 + b2 + h_target
  gemm_mfma<<<GB, blk, 0, stream>>>(ub, W2T, nullptr, b2, h_target, d_out, 128, 0);
}

// Round 4
// 374.265 us; speedup vs baseline: 2.2456x; 1.3645x over previous
//
#include <hip/hip_runtime.h>
#include <hip/hip_bf16.h>
#include <math.h>

#define HID 128

typedef __bf16 bf16x8 __attribute__((ext_vector_type(8)));
typedef float f32x4 __attribute__((ext_vector_type(4)));
union BF8 { uint4 u; bf16x8 v; unsigned short s[8]; };

__device__ __forceinline__ unsigned short f2bf(float x) {
  unsigned u = __float_as_uint(x);
  unsigned r = u + 0x7FFFu + ((u >> 16) & 1u);   // RNE (finite inputs)
  return (unsigned short)(r >> 16);
}
__device__ __forceinline__ float bf2f(unsigned short h) {
  return __uint_as_float(((unsigned)h) << 16);
}
__device__ __forceinline__ void ld2bf(const unsigned short* p, float& x, float& y) {
  unsigned v = *(const unsigned*)p;
  x = __uint_as_float((v & 0xFFFFu) << 16);
  y = __uint_as_float(v & 0xFFFF0000u);
}

// ---------- prep: transposed weights ----------
// fcT hi/lo [256][128]; WnT hi [512][128] cols=[Wl|Wr|WeA|WeB], lo [256][128] (We part);
// WpT/W1T/W2T [128][128]; bxy[256]; bpost2[128]
__global__ void prep3(const float* __restrict__ fc_W, const float* __restrict__ Wl,
                      const float* __restrict__ Wr, const float* __restrict__ We,
                      const float* __restrict__ Wpost, const float* __restrict__ W1,
                      const float* __restrict__ W2, const float* __restrict__ bl,
                      const float* __restrict__ br, const float* __restrict__ gat_bias,
                      const float* __restrict__ bpost,
                      unsigned short* __restrict__ fcTh, unsigned short* __restrict__ fcTl,
                      unsigned short* __restrict__ WnTh, unsigned short* __restrict__ WnTl,
                      unsigned short* __restrict__ WpT, unsigned short* __restrict__ W1T,
                      unsigned short* __restrict__ W2T,
                      float* __restrict__ bxy, float* __restrict__ bpost2) {
  int gid = blockIdx.x * 256 + threadIdx.x;
  if (gid < 32768) {                       // fc_W [128x256] -> fcT hi/lo [256][128]
    int n = gid >> 7, k = gid & 127;
    float x = fc_W[k * 256 + n];
    unsigned short h = f2bf(x);
    fcTh[n * 128 + k] = h;
    fcTl[n * 128 + k] = f2bf(x - bf2f(h));
  } else if (gid < 98304) {                // WnT
    int i = gid - 32768; int n = i >> 7, k = i & 127;
    float x;
    if (n < 128)      x = Wl[k * 128 + n];
    else if (n < 256) x = Wr[k * 128 + (n - 128)];
    else if (n < 384) x = We[k * 128 + (n - 256)];
    else              x = We[(128 + k) * 128 + (n - 384)];
    unsigned short h = f2bf(x);
    WnTh[n * 128 + k] = h;
    if (n >= 256) WnTl[(n - 256) * 128 + k] = f2bf(x - bf2f(h));
  } else if (gid < 147456) {               // Wpost/W1/W2 -> T [128][128]
    int i = gid - 98304; int which = i >> 14; int j = i & 16383;
    int n = j >> 7, k = j & 127;
    const float* W = (which == 0) ? Wpost : (which == 1) ? W1 : W2;
    unsigned short* T = (which == 0) ? WpT : (which == 1) ? W1T : W2T;
    T[n * 128 + k] = f2bf(W[k * 128 + n]);
  } else if (gid < 147712) {               // bxy = [bl|br]
    int j = gid - 147456;
    bxy[j] = (j < 128) ? bl[j] : br[j - 128];
  } else if (gid < 147840) {               // bpost2 = bpost + gat_bias @ Wpost
    int t = gid - 147712;
    float s = bpost[t];
    for (int k = 0; k < 128; ++k) s += gat_bias[k] * Wpost[k * 128 + t];
    bpost2[t] = s;
  }
}

// ---------- MFMA GEMM (style only): C[M x Ncols] = A[M x 128] @ WT^T + bias, split hi/lo ----------
__global__ __launch_bounds__(256) void gemm_mfma(const float* __restrict__ A,
                                                 const unsigned short* __restrict__ WTh,
                                                 const unsigned short* __restrict__ WTl,
                                                 const float* __restrict__ bias,
                                                 float* __restrict__ C, int Ncols) {
  int tid = threadIdx.x;
  int wave = tid >> 6, lane = tid & 63;
  int m = lane & 15, q = lane >> 4;
  int r0 = blockIdx.x * 64 + wave * 16;
  const float* arow = A + (size_t)(r0 + m) * 128 + q * 8;
  BF8 Ah[4], Al[4];
#pragma unroll
  for (int kc = 0; kc < 4; ++kc) {
    float4 x0 = *(const float4*)(arow + kc * 32);
    float4 x1 = *(const float4*)(arow + kc * 32 + 4);
    float xs[8] = {x0.x, x0.y, x0.z, x0.w, x1.x, x1.y, x1.z, x1.w};
#pragma unroll
    for (int j = 0; j < 8; ++j) {
      unsigned short h = f2bf(xs[j]);
      Ah[kc].s[j] = h;
      Al[kc].s[j] = f2bf(xs[j] - bf2f(h));
    }
  }
  int ntiles = Ncols >> 4;
  for (int nt = 0; nt < ntiles; ++nt) {
    const unsigned short* wr  = WTh + (size_t)(nt * 16 + m) * 128 + q * 8;
    const unsigned short* wrl = WTl + (size_t)(nt * 16 + m) * 128 + q * 8;
    f32x4 acc = {0.f, 0.f, 0.f, 0.f};
#pragma unroll
    for (int kc = 0; kc < 4; ++kc) {
      BF8 bh, blo;
      bh.u  = *(const uint4*)(wr + kc * 32);
      blo.u = *(const uint4*)(wrl + kc * 32);
      acc = __builtin_amdgcn_mfma_f32_16x16x32_bf16(Ah[kc].v, bh.v, acc, 0, 0, 0);
      acc = __builtin_amdgcn_mfma_f32_16x16x32_bf16(Al[kc].v, bh.v, acc, 0, 0, 0);
      acc = __builtin_amdgcn_mfma_f32_16x16x32_bf16(Ah[kc].v, blo.v, acc, 0, 0, 0);
    }
    int n = nt * 16 + m;
    float bv = bias ? bias[n] : 0.0f;
#pragma unroll
    for (int i = 0; i < 4; ++i) {
      int row = r0 + q * 4 + i;
      C[(size_t)row * Ncols + n] = acc[i] + bv;
    }
  }
}

// ---------- fused: GroupNorm+modulate (inline A-build) + dual-output node GEMM ----------
// out: packed [N][384] bf16 = [xl | A | B], xrArr [N][128] bf16
// wave handles 32 rows (2 A-frag sets); block 256 thr -> 128 rows; grid N/128
__global__ __launch_bounds__(256) void k_nodeP(const float* __restrict__ h_source,
                                               const float* __restrict__ style,
                                               const float* __restrict__ gn_gamma,
                                               const float* __restrict__ gn_beta,
                                               const unsigned short* __restrict__ WnTh,
                                               const unsigned short* __restrict__ WnTl,
                                               const float* __restrict__ bxy,
                                               unsigned short* __restrict__ packed,
                                               unsigned short* __restrict__ xrArr) {
  int tid = threadIdx.x, wave = tid >> 6, lane = tid & 63;
  int m = lane & 15, q = lane >> 4;
  int r0 = blockIdx.x * 128 + wave * 32;
  BF8 Ah[2][4], Al[2][4];
#pragma unroll
  for (int set = 0; set < 2; ++set) {
    int r = r0 + set * 16 + m;
    const float* hrow = h_source + (size_t)r * 128;
    const float* srow = style + (size_t)r * 256;
#pragma unroll
    for (int kc = 0; kc < 4; ++kc) {
      int ch = q * 8 + kc * 32;
      float4 x0 = *(const float4*)(hrow + ch);
      float4 x1 = *(const float4*)(hrow + ch + 4);
      float xs[8] = {x0.x, x0.y, x0.z, x0.w, x1.x, x1.y, x1.z, x1.w};
      float s8 = 0.f, q8 = 0.f;
#pragma unroll
      for (int j = 0; j < 8; ++j) { s8 += xs[j]; q8 += xs[j] * xs[j]; }
      float s16 = s8 + __shfl_xor(s8, 16);
      float q16 = q8 + __shfl_xor(q8, 16);
      float mu = s16 * (1.0f / 16.0f);
      float var = q16 * (1.0f / 16.0f) - mu * mu;
      float rv = rsqrtf(var + 1e-5f);
      float4 g0 = *(const float4*)(gn_gamma + ch);
      float4 g1 = *(const float4*)(gn_gamma + ch + 4);
      float4 be0 = *(const float4*)(gn_beta + ch);
      float4 be1 = *(const float4*)(gn_beta + ch + 4);
      float4 sg0 = *(const float4*)(srow + ch);
      float4 sg1 = *(const float4*)(srow + ch + 4);
      float4 sb0 = *(const float4*)(srow + 128 + ch);
      float4 sb1 = *(const float4*)(srow + 128 + ch + 4);
      float gg[8] = {g0.x, g0.y, g0.z, g0.w, g1.x, g1.y, g1.z, g1.w};
      float bb[8] = {be0.x, be0.y, be0.z, be0.w, be1.x, be1.y, be1.z, be1.w};
      float sg[8] = {sg0.x, sg0.y, sg0.z, sg0.w, sg1.x, sg1.y, sg1.z, sg1.w};
      float sb[8] = {sb0.x, sb0.y, sb0.z, sb0.w, sb1.x, sb1.y, sb1.z, sb1.w};
#pragma unroll
      for (int j = 0; j < 8; ++j) {
        float v = ((xs[j] - mu) * rv * gg[j] + bb[j]) * (1.0f + sg[j]) + sb[j];
        unsigned short h = f2bf(v);
        Ah[set][kc].s[j] = h;
        Al[set][kc].s[j] = f2bf(v - bf2f(h));
      }
    }
  }
  for (int nt = 0; nt < 32; ++nt) {
    f32x4 acc0 = {0.f, 0.f, 0.f, 0.f};
    f32x4 acc1 = {0.f, 0.f, 0.f, 0.f};
    const unsigned short* wr = WnTh + (size_t)(nt * 16 + m) * 128 + q * 8;
    if (nt < 16) {
#pragma unroll
      for (int kc = 0; kc < 4; ++kc) {
        BF8 bh; bh.u = *(const uint4*)(wr + kc * 32);
        acc0 = __builtin_amdgcn_mfma_f32_16x16x32_bf16(Ah[0][kc].v, bh.v, acc0, 0, 0, 0);
        acc1 = __builtin_amdgcn_mfma_f32_16x16x32_bf16(Ah[1][kc].v, bh.v, acc1, 0, 0, 0);
      }
    } else {
      const unsigned short* wl = WnTl + (size_t)((nt - 16) * 16 + m) * 128 + q * 8;
#pragma unroll
      for (int kc = 0; kc < 4; ++kc) {
        BF8 bh, blo;
        bh.u  = *(const uint4*)(wr + kc * 32);
        blo.u = *(const uint4*)(wl + kc * 32);
        acc0 = __builtin_amdgcn_mfma_f32_16x16x32_bf16(Ah[0][kc].v, bh.v, acc0, 0, 0, 0);
        acc0 = __builtin_amdgcn_mfma_f32_16x16x32_bf16(Al[0][kc].v, bh.v, acc0, 0, 0, 0);
        acc0 = __builtin_amdgcn_mfma_f32_16x16x32_bf16(Ah[0][kc].v, blo.v, acc0, 0, 0, 0);
        acc1 = __builtin_amdgcn_mfma_f32_16x16x32_bf16(Ah[1][kc].v, bh.v, acc1, 0, 0, 0);
        acc1 = __builtin_amdgcn_mfma_f32_16x16x32_bf16(Al[1][kc].v, bh.v, acc1, 0, 0, 0);
        acc1 = __builtin_amdgcn_mfma_f32_16x16x32_bf16(Ah[1][kc].v, blo.v, acc1, 0, 0, 0);
      }
    }
    int n = nt * 16 + m;
    float bv = (nt < 16) ? bxy[n] : 0.0f;
#pragma unroll
    for (int set = 0; set < 2; ++set) {
      f32x4 a = set ? acc1 : acc0;
#pragma unroll
      for (int i = 0; i < 4; ++i) {
        int row = r0 + set * 16 + q * 4 + i;
        unsigned short h = f2bf(a[i] + bv);
        if (nt < 8)       packed[(size_t)row * 384 + n] = h;
        else if (nt < 16) xrArr[(size_t)row * 128 + (n - 128)] = h;
        else              packed[(size_t)row * 384 + 128 + (n - 256)] = h;
      }
    }
  }
}

// ---------- CSR build ----------
__global__ __launch_bounds__(256) void k_hist(const int* __restrict__ edst,
                                              int* __restrict__ count, int E) {
  int e = blockIdx.x * 256 + threadIdx.x;
  if (e < E) atomicAdd(&count[edst[e]], 1);
}

__global__ __launch_bounds__(1024) void k_scan(const int* __restrict__ count,
                                               int* __restrict__ rowptr,
                                               int* __restrict__ cursor, int N, int E) {
  __shared__ int part[1024];
  int t = threadIdx.x;
  int base = t * 32;
  int local[32];
  int s = 0;
#pragma unroll
  for (int i = 0; i < 32; ++i) { local[i] = count[base + i]; s += local[i]; }
  part[t] = s;
  __syncthreads();
  for (int off = 1; off < 1024; off <<= 1) {
    int v = part[t];
    int addv = (t >= off) ? part[t - off] : 0;
    __syncthreads();
    part[t] = v + addv;
    __syncthreads();
  }
  int run = (t == 0) ? 0 : part[t - 1];
#pragma unroll
  for (int i = 0; i < 32; ++i) {
    rowptr[base + i] = run;
    cursor[base + i] = run;
    run += local[i];
  }
  if (t == 1023) rowptr[N] = E;
}

__global__ __launch_bounds__(256) void k_scatter(const int* __restrict__ esrc,
                                                 const int* __restrict__ edst,
                                                 const float* __restrict__ pos,
                                                 int* __restrict__ cursor,
                                                 float4* __restrict__ meta, int E) {
  int e = blockIdx.x * 256 + threadIdx.x;
  if (e >= E) return;
  int src = esrc[e], dst = edst[e];
  int p = atomicAdd(&cursor[dst], 1);
  float2 ps = *(const float2*)(pos + 2 * src);
  float2 pd = *(const float2*)(pos + 2 * dst);
  float dx = ps.x - pd.x, dy = ps.y - pd.y;
  float d2 = fmaxf(dx * dx + dy * dy, 1e-8f);
  meta[p] = make_float4(__int_as_float(src), -dy / d2, dx / d2, 0.0f);
}

// ---------- fused edge: logit + online softmax + aggregate; one wave per dst ----------
__device__ __forceinline__ void edge_step(float4 mt, const unsigned short* __restrict__ packed,
                                          int c0, float xr0, float xr1, float Ad0, float Ad1,
                                          float Bd0, float Bd1, float a0, float a1,
                                          float& m, float& l, float& s0, float& s1) {
  int s = __float_as_int(mt.x);
  float sy = mt.y, sx = mt.z;
  const unsigned short* pr = packed + (size_t)s * 384;
  float xl0, xl1, A0, A1, B0, B1;
  ld2bf(pr + c0, xl0, xl1);
  ld2bf(pr + 128 + c0, A0, A1);
  ld2bf(pr + 256 + c0, B0, B1);
  float z0 = xl0 + xr0 + sy * (A0 - Ad0) + sx * (B0 - Bd0);
  float z1 = xl1 + xr1 + sy * (A1 - Ad1) + sx * (B1 - Bd1);
  z0 = (z0 > 0.0f) ? z0 : 0.2f * z0;
  z1 = (z1 > 0.0f) ? z1 : 0.2f * z1;
  float p = a0 * z0 + a1 * z1;
#pragma unroll
  for (int mm = 8; mm >= 1; mm >>= 1) p += __shfl_xor(p, mm);
  float nm = fmaxf(m, p);
  float sc = expf(m - nm);   // m=-inf -> 0, no NaN (nm finite)
  float ex = expf(p - nm);
  l = l * sc + ex;
  s0 = s0 * sc + ex * xl0;
  s1 = s1 * sc + ex * xl1;
  m = nm;
}

__global__ __launch_bounds__(256) void k_edge(const int* __restrict__ rowptr,
                                              const float4* __restrict__ meta,
                                              const unsigned short* __restrict__ packed,
                                              const unsigned short* __restrict__ xrArr,
                                              const float* __restrict__ att,
                                              float* __restrict__ aggr, int N) {
  __shared__ float att_s[128];
  int tid = threadIdx.x;
  if (tid < 128) att_s[tid] = att[tid];
  __syncthreads();
  int d = blockIdx.x * 4 + (tid >> 6);
  if (d >= N) return;
  int lane = tid & 63;
  int c0 = lane * 2;
  float a0 = att_s[c0], a1 = att_s[c0 + 1];
  float xr0, xr1;
  ld2bf(xrArr + (size_t)d * 128 + c0, xr0, xr1);
  float Ad0, Ad1, Bd0, Bd1;
  ld2bf(packed + (size_t)d * 384 + 128 + c0, Ad0, Ad1);
  ld2bf(packed + (size_t)d * 384 + 256 + c0, Bd0, Bd1);

  int beg = rowptr[d], end = rowptr[d + 1];
  float m1 = -INFINITY, l1 = 0.f, p10 = 0.f, p11 = 0.f;
  float m2 = -INFINITY, l2 = 0.f, p20 = 0.f, p21 = 0.f;
  int j = beg;
  for (; j + 1 < end; j += 2) {
    float4 mta = meta[j];
    float4 mtb = meta[j + 1];
    edge_step(mta, packed, c0, xr0, xr1, Ad0, Ad1, Bd0, Bd1, a0, a1, m1, l1, p10, p11);
    edge_step(mtb, packed, c0, xr0, xr1, Ad0, Ad1, Bd0, Bd1, a0, a1, m2, l2, p20, p21);
  }
  if (j < end) {
    float4 mta = meta[j];
    edge_step(mta, packed, c0, xr0, xr1, Ad0, Ad1, Bd0, Bd1, a0, a1, m1, l1, p10, p11);
  }
  // merge state2 into state1 (sc==1 exactly when that state's m equals nm; covers empty)
  float nm = fmaxf(m1, m2);
  float sc1 = (m1 == nm) ? 1.0f : expf(m1 - nm);
  float sc2 = (m2 == nm) ? 1.0f : expf(m2 - nm);
  float l = l1 * sc1 + l2 * sc2;
  float o0 = p10 * sc1 + p20 * sc2;
  float o1 = p11 * sc1 + p21 * sc2;
  float inv = 1.0f / (l + 1e-16f);
  *(float2*)&aggr[(size_t)d * 128 + c0] = make_float2(o0 * inv, o1 * inv);
}

// ---------- fused MLP tail: t=aggr@Wpost+bpost2 -> LN -> u=gelu(t@W1+b1) -> out=u@W2+b2+resid ----------
__global__ __launch_bounds__(256) void k_mlp(const float* __restrict__ aggr,
                                             const unsigned short* __restrict__ WpT,
                                             const unsigned short* __restrict__ W1T,
                                             const unsigned short* __restrict__ W2T,
                                             const float* __restrict__ bpost2,
                                             const float* __restrict__ b1,
                                             const float* __restrict__ b2,
                                             const float* __restrict__ ln_g,
                                             const float* __restrict__ ln_b,
                                             const float* __restrict__ h_target,
                                             float* __restrict__ out) {
  __shared__ unsigned short Tb[64 * 136];
  __shared__ unsigned short Ub[64 * 136];
  int tid = threadIdx.x, wave = tid >> 6, lane = tid & 63;
  int m = lane & 15, q = lane >> 4;
  int r0 = blockIdx.x * 64 + wave * 16;
  int rb0 = wave * 16;
  // Stage A: t = aggr @ Wpost + bpost2
  BF8 Af[4];
  {
    const float* arow = aggr + (size_t)(r0 + m) * 128 + q * 8;
#pragma unroll
    for (int kc = 0; kc < 4; ++kc) {
      float4 x0 = *(const float4*)(arow + kc * 32);
      float4 x1 = *(const float4*)(arow + kc * 32 + 4);
      float xs[8] = {x0.x, x0.y, x0.z, x0.w, x1.x, x1.y, x1.z, x1.w};
#pragma unroll
      for (int jj = 0; jj < 8; ++jj) Af[kc].s[jj] = f2bf(xs[jj]);
    }
  }
  f32x4 acc[8];
#pragma unroll
  for (int t = 0; t < 8; ++t) {
    const unsigned short* wr = WpT + (size_t)(t * 16 + m) * 128 + q * 8;
    f32x4 a = {0.f, 0.f, 0.f, 0.f};
#pragma unroll
    for (int kc = 0; kc < 4; ++kc) {
      BF8 bh; bh.u = *(const uint4*)(wr + kc * 32);
      a = __builtin_amdgcn_mfma_f32_16x16x32_bf16(Af[kc].v, bh.v, a, 0, 0, 0);
    }
    acc[t] = a;
  }
  // bias + LN stats (reduce over 16 m-lanes; row r = q*4+i)
  float sum[4] = {0, 0, 0, 0}, sq[4] = {0, 0, 0, 0};
#pragma unroll
  for (int t = 0; t < 8; ++t) {
    float bv = bpost2[t * 16 + m];
#pragma unroll
    for (int i = 0; i < 4; ++i) {
      float v = acc[t][i] + bv;
      acc[t][i] = v;
      sum[i] += v;
      sq[i] += v * v;
    }
  }
#pragma unroll
  for (int i = 0; i < 4; ++i) {
#pragma unroll
    for (int w = 1; w <= 8; w <<= 1) {
      sum[i] += __shfl_xor(sum[i], w);
      sq[i] += __shfl_xor(sq[i], w);
    }
  }
  float mu[4], rv[4];
#pragma unroll
  for (int i = 0; i < 4; ++i) {
    mu[i] = sum[i] * (1.0f / 128.0f);
    float var = sq[i] * (1.0f / 128.0f) - mu[i] * mu[i];
    rv[i] = rsqrtf(var + 1e-5f);
  }
#pragma unroll
  for (int t = 0; t < 8; ++t) {
    int n = t * 16 + m;
    float g = ln_g[n], b = ln_b[n];
#pragma unroll
    for (int i = 0; i < 4; ++i) {
      float v = (acc[t][i] - mu[i]) * rv[i] * g + b;
      Tb[(rb0 + q * 4 + i) * 136 + n] = f2bf(v);
    }
  }
  __syncthreads();
  // Stage B: u = gelu(t @ W1 + b1)
  BF8 Bf[4];
  {
    const unsigned short* tp = Tb + (rb0 + m) * 136 + q * 8;
#pragma unroll
    for (int kc = 0; kc < 4; ++kc) Bf[kc].u = *(const uint4*)(tp + kc * 32);
  }
#pragma unroll
  for (int t = 0; t < 8; ++t) {
    const unsigned short* wr = W1T + (size_t)(t * 16 + m) * 128 + q * 8;
    f32x4 a = {0.f, 0.f, 0.f, 0.f};
#pragma unroll
    for (int kc = 0; kc < 4; ++kc) {
      BF8 bh; bh.u = *(const uint4*)(wr + kc * 32);
      a = __builtin_amdgcn_mfma_f32_16x16x32_bf16(Bf[kc].v, bh.v, a, 0, 0, 0);
    }
    acc[t] = a;
  }
#pragma unroll
  for (int t = 0; t < 8; ++t) {
    int n = t * 16 + m;
    float bv = b1[n];
#pragma unroll
    for (int i = 0; i < 4; ++i) {
      float v = acc[t][i] + bv;
      v = 0.5f * v * (1.0f + erff(v * 0.70710678118654752f));
      Ub[(rb0 + q * 4 + i) * 136 + n] = f2bf(v);
    }
  }
  __syncthreads();
  // Stage C: out = u @ W2 + b2 + h_target
  BF8 Cf[4];
  {
    const unsigned short* up = Ub + (rb0 + m) * 136 + q * 8;
#pragma unroll
    for (int kc = 0; kc < 4; ++kc) Cf[kc].u = *(const uint4*)(up + kc * 32);
  }
#pragma unroll
  for (int t = 0; t < 8; ++t) {
    const unsigned short* wr = W2T + (size_t)(t * 16 + m) * 128 + q * 8;
    f32x4 a = {0.f, 0.f, 0.f, 0.f};
#pragma unroll
    for (int kc = 0; kc < 4; ++kc) {
      BF8 bh; bh.u = *(const uint4*)(wr + kc * 32);
      a = __builtin_amdgcn_mfma_f32_16x16x32_bf16(Cf[kc].v, bh.v, a, 0, 0, 0);
    }
    int n = t * 16 + m;
    float bv = b2[n];
#pragma unroll
    for (int i = 0; i < 4; ++i) {
      size_t off = (size_t)(r0 + q * 4 + i) * 128 + n;
      out[off] = a[i] + bv + h_target[off];
    }
  }
}

extern "C" void kernel_launch(void* const* d_in, const int* in_sizes, int n_in,
                              void* d_out, int out_size, void* d_ws, size_t ws_size,
                              hipStream_t stream) {
  const float* h_target = (const float*)d_in[0];
  const float* h_source = (const float*)d_in[1];
  const float* pos      = (const float*)d_in[2];
  const float* t_emb    = (const float*)d_in[3];
  const int*   eidx     = (const int*)d_in[4];
  const float* gn_gamma = (const float*)d_in[5];
  const float* gn_beta  = (const float*)d_in[6];
  const float* fc_W     = (const float*)d_in[7];
  const float* fc_b     = (const float*)d_in[8];
  const float* Wl       = (const float*)d_in[9];
  const float* bl       = (const float*)d_in[10];
  const float* Wr       = (const float*)d_in[11];
  const float* br       = (const float*)d_in[12];
  const float* We       = (const float*)d_in[13];
  const float* att      = (const float*)d_in[14];
  const float* gat_bias = (const float*)d_in[15];
  const float* Wpost    = (const float*)d_in[16];
  const float* bpost    = (const float*)d_in[17];
  const float* ln_g     = (const float*)d_in[18];
  const float* ln_b     = (const float*)d_in[19];
  const float* W1       = (const float*)d_in[20];
  const float* b1       = (const float*)d_in[21];
  const float* W2       = (const float*)d_in[22];
  const float* b2       = (const float*)d_in[23];

  const int N = in_sizes[0] / HID;     // 32768
  const int E = in_sizes[4] / 2;       // 524288
  const int* esrc = eidx;
  const int* edst = eidx + E;

  // ---- workspace (float offsets; MF = 1M floats = 4MB) ----
  // [0,8MF):   style fp32 (dead after k_nodeP) -> aggr fp32 [0,4MF)
  // [8,14MF):  packed bf16 [N][384]
  // [14,16MF): xrArr bf16 [N][128]
  // [16,18MF): meta float4 [E]
  // [18MF,..): rowptr/count/cursor, weights, biases
  float* ws = (float*)d_ws;
  const size_t MF = 1024 * 1024;
  float* style  = ws;
  float* aggr   = ws;
  unsigned short* packed = (unsigned short*)(ws + 8 * MF);
  unsigned short* xrArr  = (unsigned short*)(ws + 14 * MF);
  float4* meta  = (float4*)(ws + 16 * MF);
  int*   rowptr = (int*)(ws + 18 * MF);
  int*   count  = rowptr + 32832;
  int*   cursor = count + 32832;
  unsigned short* wgt = (unsigned short*)(ws + 18 * MF + 131072);
  unsigned short* fcTh = wgt;
  unsigned short* fcTl = wgt + 32768;
  unsigned short* WnTh = wgt + 65536;
  unsigned short* WnTl = wgt + 131072;
  unsigned short* WpT  = wgt + 163840;
  unsigned short* W1T  = wgt + 180224;
  unsigned short* W2T  = wgt + 196608;
  float* bxy    = (float*)(wgt + 212992);
  float* bpost2 = bxy + 256;
  const size_t needed = (size_t)(18 * MF + 131072 + 106496 + 512) * 4;
  if (ws_size < needed) return;  // visible failure (out stays poisoned)

  dim3 blk(256);

  // 1. prep
  prep3<<<578, blk, 0, stream>>>(fc_W, Wl, Wr, We, Wpost, W1, W2, bl, br, gat_bias, bpost,
                                 fcTh, fcTl, WnTh, WnTl, WpT, W1T, W2T, bxy, bpost2);
  // 2. style = t_emb @ fc_W + fc_b  [N x 256]  (split precision)
  gemm_mfma<<<N / 64, blk, 0, stream>>>(t_emb, fcTh, fcTl, fc_b, style, 256);
  // 3. fused GN+modulate + node GEMM -> packed [xl|A|B] bf16, xr bf16
  k_nodeP<<<N / 128, blk, 0, stream>>>(h_source, style, gn_gamma, gn_beta, WnTh, WnTl, bxy,
                                       packed, xrArr);
  // 4. CSR build
  hipMemsetAsync(count, 0, (size_t)N * 4, stream);
  k_hist<<<(E + 255) / 256, blk, 0, stream>>>(edst, count, E);
  k_scan<<<1, 1024, 0, stream>>>(count, rowptr, cursor, N, E);
  k_scatter<<<(E + 255) / 256, blk, 0, stream>>>(esrc, edst, pos, cursor, meta, E);
  // 5. fused edge pass -> aggr (style region now dead)
  k_edge<<<(N + 3) / 4, blk, 0, stream>>>(rowptr, meta, packed, xrArr, att, aggr, N);
  // 6. fused MLP tail -> out
  k_mlp<<<N / 64, blk, 0, stream>>>(aggr, WpT, W1T, W2T, bpost2, b1, b2, ln_g, ln_b,
                                    h_target, (float*)d_out);
}